// Round 3
// baseline (373.677 us; speedup 1.0000x reference)
//
#include <hip/hip_runtime.h>

#define NN 100000
#define NE 1200000
#define NG 2048
#define VOCAB 10000
#define D 64
#define C 2

#define NBK 196      // coarse buckets of 512 nodes (dst >> 9)
#define BSH 9
#define SLOT 7168    // per-bucket slot stride; mean 6144, sd 78 -> +13 sigma

typedef _Float16 half8 __attribute__((ext_vector_type(8)));

__device__ __forceinline__ int atomAddI(int* p, int v) {
    return __hip_atomic_fetch_add(p, v, __ATOMIC_RELAXED, __HIP_MEMORY_SCOPE_AGENT);
}
__device__ __forceinline__ void atomAddF(float* p, float v) {
    __hip_atomic_fetch_add(p, v, __ATOMIC_RELAXED, __HIP_MEMORY_SCOPE_AGENT);
}

// ---------------- emb -> fp16 copy (1.28 MB, L2-resident everywhere) ----------------
__global__ void __launch_bounds__(256) k_embh(const float4* __restrict__ emb4,
        half8* __restrict__ embh) {
    int i = blockIdx.x * 256 + threadIdx.x;
    if (i >= VOCAB * 8) return;
    float4 a = emb4[(size_t)i * 2], b = emb4[(size_t)i * 2 + 1];
    half8 h;
    h[0] = (_Float16)a.x; h[1] = (_Float16)a.y; h[2] = (_Float16)a.z; h[3] = (_Float16)a.w;
    h[4] = (_Float16)b.x; h[5] = (_Float16)b.y; h[6] = (_Float16)b.z; h[7] = (_Float16)b.w;
    embh[i] = h;
}

// ---------------- phase A: coarse bucket scatter (packed src|dlow) ----------------
__global__ void __launch_bounds__(256) k_bucket(const int* __restrict__ src,
        const int* __restrict__ dst, int* __restrict__ bcur, unsigned* __restrict__ barr) {
    __shared__ int hcnt[NBK], hbase[NBK], hrank[NBK];
    int tid = threadIdx.x;
    if (tid < NBK) { hcnt[tid] = 0; hrank[tid] = 0; }
    __syncthreads();
    int per = (NE + gridDim.x - 1) / gridDim.x;
    int e0 = blockIdx.x * per, e1 = min(e0 + per, NE);
    for (int e = e0 + tid; e < e1; e += 256)
        atomicAdd(&hcnt[dst[e] >> BSH], 1);
    __syncthreads();
    if (tid < NBK) {
        int c = hcnt[tid];
        hbase[tid] = c ? atomAddI(&bcur[tid], c) : 0;
    }
    __syncthreads();
    for (int e = e0 + tid; e < e1; e += 256) {
        int d = dst[e], s = src[e];
        int b = d >> BSH;
        int r = atomicAdd(&hrank[b], 1);
        barr[(size_t)b * SLOT + hbase[b] + r] = ((unsigned)s << BSH) | (unsigned)(d & 511);
    }
}

// ---------------- bucket-count scan ----------------
__global__ void __launch_bounds__(256) k_bscan(const int* __restrict__ bcur,
        int* __restrict__ bstart, int* __restrict__ start) {
    __shared__ int sm[256];
    int t = threadIdx.x;
    int v0 = (t < NBK) ? bcur[t] : 0;
    sm[t] = v0;
    __syncthreads();
    for (int off = 1; off < 256; off <<= 1) {
        int v = (t >= off) ? sm[t - off] : 0;
        __syncthreads();
        sm[t] += v;
        __syncthreads();
    }
    if (t < NBK) bstart[t] = sm[t] - v0;
    if (t == 0) { bstart[NBK] = NE; start[NN] = NE; }
}

// ---------------- phase B: exact CSR within each bucket; also emits u16 xcsr ----------------
__global__ void __launch_bounds__(256) k_sortb(const int* __restrict__ bcur,
        const int* __restrict__ bstart, const unsigned* __restrict__ barr,
        const int* __restrict__ x,
        int* __restrict__ start, int* __restrict__ csr, unsigned short* __restrict__ xcsr) {
    __shared__ int cnt[512], loc[512], sm[256];
    int t = threadIdx.x;
    int b = blockIdx.x;
    cnt[t] = 0; cnt[t + 256] = 0;
    __syncthreads();
    int count = bcur[b];
    int base  = bstart[b];
    const unsigned* bp = barr + (size_t)b * SLOT;
    for (int i = t; i < count; i += 256)
        atomicAdd(&cnt[bp[i] & 511], 1);
    __syncthreads();
    int c0 = cnt[2 * t], c1 = cnt[2 * t + 1];
    int s = c0 + c1;
    sm[t] = s;
    __syncthreads();
    for (int off = 1; off < 256; off <<= 1) {
        int v = (t >= off) ? sm[t - off] : 0;
        __syncthreads();
        sm[t] += v;
        __syncthreads();
    }
    int ex = sm[t] - s;
    loc[2 * t] = ex; loc[2 * t + 1] = ex + c0;
    int g0 = b << BSH;
    if (g0 + 2 * t < NN)     start[g0 + 2 * t]     = base + ex;
    if (g0 + 2 * t + 1 < NN) start[g0 + 2 * t + 1] = base + ex + c0;
    __syncthreads();
    for (int i = t; i < count; i += 256) {
        unsigned p = bp[i];
        int r = atomicAdd(&loc[p & 511], 1);
        int sn = (int)(p >> BSH);
        csr[base + r]  = sn;
        xcsr[base + r] = (unsigned short)x[sn];   // VOCAB=10000 < 65536
    }
}

// ---------------- layer-1 aggregate: FULL 128B fp16 row gather from emb_h ----------------
// emb_h = 1.28 MB -> L2-resident on every XCD. 8 lanes x half8 per row,
// 8 nodes/wave, 32 nodes/block. 2 line-touches per edge (was 8).
// Output agg layout: fp32 [4][NN][16] (chunk c = dims 16c..16c+15).
__global__ void __launch_bounds__(256) k_agg1(const int* __restrict__ start,
        const unsigned short* __restrict__ idx, const half8* __restrict__ embh,
        float* __restrict__ aggT) {
    int tid = threadIdx.x;
    int lane = tid & 63, wave = tid >> 6;
    int f = lane & 7;          // which half8 of the 64-dim row
    int nsub = lane >> 3;      // 8 nodes per wave
    int n = blockIdx.x * 32 + wave * 8 + nsub;

    float pf = 0.f;
    {   // streaming warm of emb_h (covered once device-wide; rest self-warms)
        int i = blockIdx.x * 256 + tid;
        if (i < VOCAB * 8) { float4 v = ((const float4*)embh)[i]; pf = v.x; }
    }
    asm volatile("" : "+v"(pf));
    if (n >= NN) return;

    int s0 = start[n], s1 = start[n + 1];
    float inv = 1.0f / (float)max(s1 - s0, 1);
    float a[8] = {0.f, 0.f, 0.f, 0.f, 0.f, 0.f, 0.f, 0.f};
    int i = s0;
    for (; i + 4 <= s1; i += 4) {
        int c0 = idx[i], c1 = idx[i + 1], c2 = idx[i + 2], c3 = idx[i + 3];
        half8 v0 = embh[(size_t)c0 * 8 + f];
        half8 v1 = embh[(size_t)c1 * 8 + f];
        half8 v2 = embh[(size_t)c2 * 8 + f];
        half8 v3 = embh[(size_t)c3 * 8 + f];
#pragma unroll
        for (int k = 0; k < 8; ++k)
            a[k] += ((float)v0[k] + (float)v1[k]) + ((float)v2[k] + (float)v3[k]);
    }
    for (; i < s1; ++i) {
        half8 v = embh[(size_t)idx[i] * 8 + f];
#pragma unroll
        for (int k = 0; k < 8; ++k) a[k] += (float)v[k];
    }
    float4 o0, o1;
    o0.x = a[0] * inv; o0.y = a[1] * inv; o0.z = a[2] * inv; o0.w = a[3] * inv;
    o1.x = a[4] * inv; o1.y = a[5] * inv; o1.z = a[6] * inv; o1.w = a[7] * inv;
    float4* op = (float4*)(aggT + ((size_t)(f >> 1) * NN + n) * 16 + (f & 1) * 8);
    op[0] = o0; op[1] = o1;
}

// ---------------- layer-2 aggregate: 4-chunk fp16 gather from h1 ----------------
// chunk slab = NN*16 fp16 = 3.2 MB (per-XCD L2-resident). c = bid&3,
// node-half = bid bit2 -> each XCD streams only half the csr (idx fetch halved).
// 2 lanes x half8 per chunk-row; 32 nodes/wave. 4 line-touches/edge (was 8).
__global__ void __launch_bounds__(256) k_agg2h(const int* __restrict__ start,
        const int* __restrict__ idx, const half8* __restrict__ gsrc,
        float* __restrict__ aggT) {
    int tid = threadIdx.x;
    int lane = tid & 63, wave = tid >> 6;
    int c     = blockIdx.x & 3;
    int half_ = (blockIdx.x >> 2) & 1;
    int nb    = blockIdx.x >> 3;         // 0..390
    int f4 = lane & 1, nsub = lane >> 1; // 32 nodes per wave
    const half8* gsl = gsrc + (size_t)c * NN * 2;

    float pf = 0.f;
    {   // warm this XCD's share of the chunk slab (other half self-warms)
        int i = half_ * 100000 + nb * 256 + tid;
        if (i < NN * 2) { float4 v = ((const float4*)gsl)[i]; pf = v.x; }
    }
    asm volatile("" : "+v"(pf));

    int nloc = nb * 128 + wave * 32 + nsub;
    if (nloc >= NN / 2) return;
    int n = half_ * (NN / 2) + nloc;
    int s0 = start[n], s1 = start[n + 1];
    float inv = 1.0f / (float)max(s1 - s0, 1);
    float a[8] = {0.f, 0.f, 0.f, 0.f, 0.f, 0.f, 0.f, 0.f};
    int i = s0;
    for (; i + 4 <= s1; i += 4) {
        int c0 = idx[i], c1 = idx[i + 1], c2 = idx[i + 2], c3 = idx[i + 3];
        half8 v0 = gsl[(size_t)c0 * 2 + f4];
        half8 v1 = gsl[(size_t)c1 * 2 + f4];
        half8 v2 = gsl[(size_t)c2 * 2 + f4];
        half8 v3 = gsl[(size_t)c3 * 2 + f4];
#pragma unroll
        for (int k = 0; k < 8; ++k)
            a[k] += ((float)v0[k] + (float)v1[k]) + ((float)v2[k] + (float)v3[k]);
    }
    for (; i < s1; ++i) {
        half8 v = gsl[(size_t)idx[i] * 2 + f4];
#pragma unroll
        for (int k = 0; k < 8; ++k) a[k] += (float)v[k];
    }
    float4 o0, o1;
    o0.x = a[0] * inv; o0.y = a[1] * inv; o0.z = a[2] * inv; o0.w = a[3] * inv;
    o1.x = a[4] * inv; o1.y = a[5] * inv; o1.z = a[6] * inv; o1.w = a[7] * inv;
    float4* op = (float4*)(aggT + ((size_t)c * NN + n) * 16 + f4 * 8);
    op[0] = o0; op[1] = o1;
}

// ---------------- layer-1 linear (+ReLU) -> fp16 h1 ----------------
// one thread per (node, output-quarter h). agg fp32 [4][NN][16]; root = emb[x[n]] fp32.
// output chunk h of T0h fp16 [4][NN][16] (dims h*16..h*16+15 = exactly chunk h).
__global__ void __launch_bounds__(256) k_lin1(const float* __restrict__ aggT,
        const int* __restrict__ x, const float4* __restrict__ emb4,
        const float* __restrict__ Wl, const float* __restrict__ bl,
        const float* __restrict__ Wr, half8* __restrict__ outh) {
    int tid = blockIdx.x * 256 + threadIdx.x;
    int h = blockIdx.y;                // 0..3
    int n = tid < NN ? tid : NN - 1;   // clamp; store guarded

    float acc[16];
#pragma unroll
    for (int d = 0; d < 16; ++d) acc[d] = bl[h * 16 + d];

    const float4* ap = (const float4*)aggT + (size_t)n * 4;
    const float4* rp = emb4 + (size_t)x[n] * 16;
    const size_t cstep = (size_t)NN * 4;     // chunk stride in float4s
    const float* WlH = Wl + h * 16 * 64;
    const float* WrH = Wr + h * 16 * 64;

    float4 A[4], R[4];
#pragma unroll
    for (int j = 0; j < 4; ++j) { A[j] = ap[j]; R[j] = rp[j]; }
#pragma unroll
    for (int c = 0; c < 4; ++c) {
        float av[16], rv[16];
#pragma unroll
        for (int j = 0; j < 4; ++j) {
            av[4 * j + 0] = A[j].x; av[4 * j + 1] = A[j].y; av[4 * j + 2] = A[j].z; av[4 * j + 3] = A[j].w;
            rv[4 * j + 0] = R[j].x; rv[4 * j + 1] = R[j].y; rv[4 * j + 2] = R[j].z; rv[4 * j + 3] = R[j].w;
        }
        if (c < 3) {
#pragma unroll
            for (int j = 0; j < 4; ++j) {
                A[j] = ap[(size_t)(c + 1) * cstep + j];
                R[j] = rp[(c + 1) * 4 + j];
            }
        }
        const float* wl = WlH + c * 16;
        const float* wr = WrH + c * 16;
#pragma unroll
        for (int d = 0; d < 16; ++d) {
#pragma unroll
            for (int k = 0; k < 16; ++k) {
                acc[d] += av[k] * wl[d * 64 + k];
                acc[d] += rv[k] * wr[d * 64 + k];
            }
        }
    }

    if (tid < NN) {
        half8 o0, o1;
#pragma unroll
        for (int k = 0; k < 8; ++k) {
            o0[k] = (_Float16)fmaxf(acc[k], 0.f);
            o1[k] = (_Float16)fmaxf(acc[8 + k], 0.f);
        }
        half8* op = outh + ((size_t)h * NN + n) * 2;
        op[0] = o0; op[1] = o1;
    }
}

// ---------------- layer-2 linear FUSED with per-graph pool ----------------
// agg fp32 [4][NN][16]; root = h1 fp16 [4][NN][16]. After ReLU, wave-level
// segmented scan over sorted batch keys; segment-last lane atomAdds into pooled.
__global__ void __launch_bounds__(256) k_lin2p(const float* __restrict__ aggT,
        const half8* __restrict__ rooth, const int* __restrict__ batch,
        const float* __restrict__ Wl, const float* __restrict__ bl,
        const float* __restrict__ Wr, float* __restrict__ pooled) {
    int tid = blockIdx.x * 256 + threadIdx.x;
    int h = blockIdx.y;                // 0..3
    bool valid = tid < NN;
    int n = valid ? tid : NN - 1;      // clamp; contribution zeroed below

    float acc[16];
#pragma unroll
    for (int d = 0; d < 16; ++d) acc[d] = bl[h * 16 + d];

    const float4* ap  = (const float4*)aggT + (size_t)n * 4;
    const half8*  rph = rooth + (size_t)n * 2;
    const size_t cstep  = (size_t)NN * 4;   // agg chunk stride in float4s
    const size_t rcstep = (size_t)NN * 2;   // root chunk stride in half8s
    const float* WlH = Wl + h * 16 * 64;
    const float* WrH = Wr + h * 16 * 64;

    float4 A[4]; half8 Rh[2];
#pragma unroll
    for (int j = 0; j < 4; ++j) A[j] = ap[j];
    Rh[0] = rph[0]; Rh[1] = rph[1];
#pragma unroll
    for (int c = 0; c < 4; ++c) {
        float av[16], rv[16];
#pragma unroll
        for (int j = 0; j < 4; ++j) {
            av[4 * j + 0] = A[j].x; av[4 * j + 1] = A[j].y; av[4 * j + 2] = A[j].z; av[4 * j + 3] = A[j].w;
        }
#pragma unroll
        for (int k = 0; k < 8; ++k) { rv[k] = (float)Rh[0][k]; rv[8 + k] = (float)Rh[1][k]; }
        if (c < 3) {
#pragma unroll
            for (int j = 0; j < 4; ++j) A[j] = ap[(size_t)(c + 1) * cstep + j];
            Rh[0] = rph[(size_t)(c + 1) * rcstep];
            Rh[1] = rph[(size_t)(c + 1) * rcstep + 1];
        }
        const float* wl = WlH + c * 16;
        const float* wr = WrH + c * 16;
#pragma unroll
        for (int d = 0; d < 16; ++d) {
#pragma unroll
            for (int k = 0; k < 16; ++k) {
                acc[d] += av[k] * wl[d * 64 + k];
                acc[d] += rv[k] * wr[d * 64 + k];
            }
        }
    }

    // ---- fused pool: segmented wave scan over sorted batch ----
    int lane = threadIdx.x & 63;
    int g = batch[n];
    int g1  = __shfl_up(g, 1);
    int g2  = __shfl_up(g, 2);
    int g4  = __shfl_up(g, 4);
    int g8  = __shfl_up(g, 8);
    int g16 = __shfl_up(g, 16);
    int g32 = __shfl_up(g, 32);
    bool s1  = (lane >= 1)  && (g1 == g);
    bool s2  = (lane >= 2)  && (g2 == g);
    bool s4  = (lane >= 4)  && (g4 == g);
    bool s8  = (lane >= 8)  && (g8 == g);
    bool s16 = (lane >= 16) && (g16 == g);
    bool s32 = (lane >= 32) && (g32 == g);
    int gn = __shfl_down(g, 1);
    bool isLast = (lane == 63) || (gn != g);
    float* pg = pooled + (size_t)g * D + h * 16;
#pragma unroll
    for (int d = 0; d < 16; ++d) {
        float v = valid ? fmaxf(acc[d], 0.f) : 0.f;
        float t;
        t = __shfl_up(v, 1);  v += s1  ? t : 0.f;
        t = __shfl_up(v, 2);  v += s2  ? t : 0.f;
        t = __shfl_up(v, 4);  v += s4  ? t : 0.f;
        t = __shfl_up(v, 8);  v += s8  ? t : 0.f;
        t = __shfl_up(v, 16); v += s16 ? t : 0.f;
        t = __shfl_up(v, 32); v += s32 ? t : 0.f;
        if (isLast) atomAddF(pg + d, v);
    }
}

// ---------------- readout ----------------
__global__ void __launch_bounds__(256) k_bounds(const int* __restrict__ batch, int* __restrict__ gs) {
    int n = blockIdx.x * blockDim.x + threadIdx.x;
    if (n >= NN) return;
    int b = batch[n];
    if (n == 0) {
        for (int g = 0; g <= b; ++g) gs[g] = 0;
    } else {
        int bp = batch[n - 1];
        for (int g = bp + 1; g <= b; ++g) gs[g] = n;
    }
    if (n == NN - 1) {
        for (int g = b + 1; g <= NG; ++g) gs[g] = NN;
    }
}

__global__ void __launch_bounds__(256) k_out(const int* __restrict__ gs,
        const float* __restrict__ pooled, const float* __restrict__ Wout,
        const float* __restrict__ bout, float* __restrict__ out) {
    int lane = threadIdx.x & 63;
    int wave = threadIdx.x >> 6;
    int g = blockIdx.x * 4 + wave;       // 512 blocks
    int s0 = gs[g], s1 = gs[g + 1];
    float p = pooled[(size_t)g * D + lane] / (float)max(s1 - s0, 1);
    float c0 = p * Wout[lane];
    float c1 = p * Wout[D + lane];
#pragma unroll
    for (int off = 32; off > 0; off >>= 1) {
        c0 += __shfl_down(c0, off, 64);
        c1 += __shfl_down(c1, off, 64);
    }
    if (lane == 0) {
        out[g * C + 0] = c0 + bout[0];
        out[g * C + 1] = c1 + bout[1];
    }
}

extern "C" void kernel_launch(void* const* d_in, const int* in_sizes, int n_in,
                              void* d_out, int out_size, void* d_ws, size_t ws_size,
                              hipStream_t stream) {
    const int*   x     = (const int*)d_in[0];
    const int*   src   = (const int*)d_in[1];
    const int*   dst   = src + NE;
    const int*   batch = (const int*)d_in[2];
    const float* emb   = (const float*)d_in[3];
    const float* W1l   = (const float*)d_in[4];
    const float* b1l   = (const float*)d_in[5];
    const float* W1r   = (const float*)d_in[6];
    const float* W2l   = (const float*)d_in[7];
    const float* b2l   = (const float*)d_in[8];
    const float* W2r   = (const float*)d_in[9];
    const float* Wout  = (const float*)d_in[10];
    const float* bout  = (const float*)d_in[11];
    float* out = (float*)d_out;

    float*    TA   = (float*)d_ws;                          // NN*64 fp32 agg slabs [4][NN][16]
    _Float16* T0h  = (_Float16*)(TA + (size_t)NN * 64);     // NN*64 fp16 h1 [4][NN][16]
    _Float16* embh = T0h + (size_t)NN * 64;                 // VOCAB*64 fp16
    float* pooled  = (float*)(embh + (size_t)VOCAB * 64);   // NG*64
    int* bcur   = (int*)(pooled + (size_t)NG * 64);         // NBK (contiguous w/ pooled for memset)
    int* bstart = bcur + NBK;                               // NBK+1
    int* startA = bstart + NBK + 1;                         // NN+1
    int* gs     = startA + NN + 1;                          // NG+1
    int* csr    = gs + NG + 1;                              // NE
    unsigned short* xcsr = (unsigned short*)(csr + NE);     // NE u16
    unsigned* barr = (unsigned*)(xcsr + NE);                // NBK*SLOT (~5.6 MB)

    hipMemsetAsync(pooled, 0, ((size_t)NG * 64 + NBK) * sizeof(float), stream);

    k_embh  <<<(VOCAB * 8 + 255) / 256, 256, 0, stream>>>((const float4*)emb, (half8*)embh);
    k_bucket<<<192, 256, 0, stream>>>(src, dst, bcur, barr);
    k_bscan <<<1, 256, 0, stream>>>(bcur, bstart, startA);
    k_sortb <<<NBK, 256, 0, stream>>>(bcur, bstart, barr, x, startA, csr, xcsr);
    k_bounds<<<(NN + 255) / 256, 256, 0, stream>>>(batch, gs);

    dim3 linGrid((NN + 255) / 256, 4);
    // ---- layer 1: full-row fp16 gather from emb_h; root from fp32 emb[x[n]] ----
    k_agg1<<<NN / 32, 256, 0, stream>>>(startA, xcsr, (const half8*)embh, TA);
    k_lin1<<<linGrid, 256, 0, stream>>>(TA, x, (const float4*)emb,
                                        W1l, b1l, W1r, (half8*)T0h);
    // ---- layer 2: 4-chunk fp16 gather; linear fused with per-graph pool ----
    k_agg2h<<<((NN / 2 + 127) / 128) * 8, 256, 0, stream>>>(startA, csr, (const half8*)T0h, TA);
    k_lin2p<<<linGrid, 256, 0, stream>>>(TA, (const half8*)T0h, batch,
                                         W2l, b2l, W2r, pooled);

    // ---- readout ----
    k_out<<<NG / 4, 256, 0, stream>>>(gs, pooled, Wout, bout, out);
}

// Round 4
// 265.059 us; speedup vs baseline: 1.4098x; 1.4098x over previous
//
#include <hip/hip_runtime.h>

#define NN 100000
#define NE 1200000
#define NG 2048
#define VOCAB 10000
#define D 64
#define C 2

#define NBK 196      // coarse buckets of 512 nodes (dst >> 9)
#define BSH 9
#define SLOT 7168    // per-bucket slot stride; mean 6144, sd 78 -> +13 sigma

typedef _Float16 half8 __attribute__((ext_vector_type(8)));

__device__ __forceinline__ int atomAddI(int* p, int v) {
    return __hip_atomic_fetch_add(p, v, __ATOMIC_RELAXED, __HIP_MEMORY_SCOPE_AGENT);
}
__device__ __forceinline__ void atomAddF(float* p, float v) {
    __hip_atomic_fetch_add(p, v, __ATOMIC_RELAXED, __HIP_MEMORY_SCOPE_AGENT);
}

// ---------------- emb -> fp16 copy (1.28 MB, L2-resident everywhere) ----------------
__global__ void __launch_bounds__(256) k_embh(const float4* __restrict__ emb4,
        half8* __restrict__ embh) {
    int i = blockIdx.x * 256 + threadIdx.x;
    if (i >= VOCAB * 8) return;
    float4 a = emb4[(size_t)i * 2], b = emb4[(size_t)i * 2 + 1];
    half8 h;
    h[0] = (_Float16)a.x; h[1] = (_Float16)a.y; h[2] = (_Float16)a.z; h[3] = (_Float16)a.w;
    h[4] = (_Float16)b.x; h[5] = (_Float16)b.y; h[6] = (_Float16)b.z; h[7] = (_Float16)b.w;
    embh[i] = h;
}

// ---------------- phase A: coarse bucket scatter (packed src|dlow) ----------------
__global__ void __launch_bounds__(256) k_bucket(const int* __restrict__ src,
        const int* __restrict__ dst, int* __restrict__ bcur, unsigned* __restrict__ barr) {
    __shared__ int hcnt[NBK], hbase[NBK], hrank[NBK];
    int tid = threadIdx.x;
    if (tid < NBK) { hcnt[tid] = 0; hrank[tid] = 0; }
    __syncthreads();
    int per = (NE + gridDim.x - 1) / gridDim.x;
    int e0 = blockIdx.x * per, e1 = min(e0 + per, NE);
    for (int e = e0 + tid; e < e1; e += 256)
        atomicAdd(&hcnt[dst[e] >> BSH], 1);
    __syncthreads();
    if (tid < NBK) {
        int c = hcnt[tid];
        hbase[tid] = c ? atomAddI(&bcur[tid], c) : 0;
    }
    __syncthreads();
    for (int e = e0 + tid; e < e1; e += 256) {
        int d = dst[e], s = src[e];
        int b = d >> BSH;
        int r = atomicAdd(&hrank[b], 1);
        barr[(size_t)b * SLOT + hbase[b] + r] = ((unsigned)s << BSH) | (unsigned)(d & 511);
    }
}

// ---------------- bucket-count scan ----------------
__global__ void __launch_bounds__(256) k_bscan(const int* __restrict__ bcur,
        int* __restrict__ bstart, int* __restrict__ start) {
    __shared__ int sm[256];
    int t = threadIdx.x;
    int v0 = (t < NBK) ? bcur[t] : 0;
    sm[t] = v0;
    __syncthreads();
    for (int off = 1; off < 256; off <<= 1) {
        int v = (t >= off) ? sm[t - off] : 0;
        __syncthreads();
        sm[t] += v;
        __syncthreads();
    }
    if (t < NBK) bstart[t] = sm[t] - v0;
    if (t == 0) { bstart[NBK] = NE; start[NN] = NE; }
}

// ---------------- phase B: exact CSR within each bucket; also emits u16 xcsr ----------------
__global__ void __launch_bounds__(256) k_sortb(const int* __restrict__ bcur,
        const int* __restrict__ bstart, const unsigned* __restrict__ barr,
        const int* __restrict__ x,
        int* __restrict__ start, int* __restrict__ csr, unsigned short* __restrict__ xcsr) {
    __shared__ int cnt[512], loc[512], sm[256];
    int t = threadIdx.x;
    int b = blockIdx.x;
    cnt[t] = 0; cnt[t + 256] = 0;
    __syncthreads();
    int count = bcur[b];
    int base  = bstart[b];
    const unsigned* bp = barr + (size_t)b * SLOT;
    for (int i = t; i < count; i += 256)
        atomicAdd(&cnt[bp[i] & 511], 1);
    __syncthreads();
    int c0 = cnt[2 * t], c1 = cnt[2 * t + 1];
    int s = c0 + c1;
    sm[t] = s;
    __syncthreads();
    for (int off = 1; off < 256; off <<= 1) {
        int v = (t >= off) ? sm[t - off] : 0;
        __syncthreads();
        sm[t] += v;
        __syncthreads();
    }
    int ex = sm[t] - s;
    loc[2 * t] = ex; loc[2 * t + 1] = ex + c0;
    int g0 = b << BSH;
    if (g0 + 2 * t < NN)     start[g0 + 2 * t]     = base + ex;
    if (g0 + 2 * t + 1 < NN) start[g0 + 2 * t + 1] = base + ex + c0;
    __syncthreads();
    for (int i = t; i < count; i += 256) {
        unsigned p = bp[i];
        int r = atomicAdd(&loc[p & 511], 1);
        int sn = (int)(p >> BSH);
        csr[base + r]  = sn;
        xcsr[base + r] = (unsigned short)x[sn];   // VOCAB=10000 < 65536
    }
}

// ---------------- layer-1 aggregate: FULL 128B fp16 row gather from emb_h ----------------
// emb_h = 1.28 MB -> L2-resident on every XCD. 8 lanes x half8 per row,
// 8 nodes/wave, 32 nodes/block. 2 line-touches per edge (was 8 in fp32 chunked).
// Output agg layout: fp32 [8][NN][8] (slab s = dims 8s..8s+7) -- round-2 lin layout.
__global__ void __launch_bounds__(256) k_agg1(const int* __restrict__ start,
        const unsigned short* __restrict__ idx, const half8* __restrict__ embh,
        float* __restrict__ aggT) {
    int tid = threadIdx.x;
    int lane = tid & 63, wave = tid >> 6;
    int f = lane & 7;          // which half8 of the 64-dim row
    int nsub = lane >> 3;      // 8 nodes per wave
    int n = blockIdx.x * 32 + wave * 8 + nsub;

    float pf = 0.f;
    {   // streaming warm of emb_h (covered once device-wide; rest self-warms)
        int i = blockIdx.x * 256 + tid;
        if (i < VOCAB * 8) { float4 v = ((const float4*)embh)[i]; pf = v.x; }
    }
    asm volatile("" : "+v"(pf));
    if (n >= NN) return;

    int s0 = start[n], s1 = start[n + 1];
    float inv = 1.0f / (float)max(s1 - s0, 1);
    float a[8] = {0.f, 0.f, 0.f, 0.f, 0.f, 0.f, 0.f, 0.f};
    int i = s0;
    for (; i + 4 <= s1; i += 4) {
        int c0 = idx[i], c1 = idx[i + 1], c2 = idx[i + 2], c3 = idx[i + 3];
        half8 v0 = embh[(size_t)c0 * 8 + f];
        half8 v1 = embh[(size_t)c1 * 8 + f];
        half8 v2 = embh[(size_t)c2 * 8 + f];
        half8 v3 = embh[(size_t)c3 * 8 + f];
#pragma unroll
        for (int k = 0; k < 8; ++k)
            a[k] += ((float)v0[k] + (float)v1[k]) + ((float)v2[k] + (float)v3[k]);
    }
    for (; i < s1; ++i) {
        half8 v = embh[(size_t)idx[i] * 8 + f];
#pragma unroll
        for (int k = 0; k < 8; ++k) a[k] += (float)v[k];
    }
    float4 o0, o1;
    o0.x = a[0] * inv; o0.y = a[1] * inv; o0.z = a[2] * inv; o0.w = a[3] * inv;
    o1.x = a[4] * inv; o1.y = a[5] * inv; o1.z = a[6] * inv; o1.w = a[7] * inv;
    float4* op = (float4*)(aggT + ((size_t)f * NN + n) * 8);
    op[0] = o0; op[1] = o1;
}

// ---------------- layer-2 aggregate: 4-chunk fp16 gather from h1 ----------------
// h1 chunk slab = NN*16 fp16 = 3.2 MB (per-XCD L2-resident). c = bid&3,
// node-half = bid bit2 -> each XCD streams only half the csr (idx fetch halved).
// 2 lanes x half8 per chunk-row; 32 nodes/wave. 4 line-touches/edge (was 8).
// Output agg fp32 [8][NN][8]: slab 2c+f4 = dims 16c+8*f4 .. +7.
__global__ void __launch_bounds__(256) k_agg2h(const int* __restrict__ start,
        const int* __restrict__ idx, const half8* __restrict__ gsrc,
        float* __restrict__ aggT) {
    int tid = threadIdx.x;
    int lane = tid & 63, wave = tid >> 6;
    int c     = blockIdx.x & 3;
    int half_ = (blockIdx.x >> 2) & 1;
    int nb    = blockIdx.x >> 3;         // 0..390
    int f4 = lane & 1, nsub = lane >> 1; // 32 nodes per wave
    const half8* gsl = gsrc + (size_t)c * NN * 2;

    float pf = 0.f;
    {   // warm this XCD's share of the chunk slab (other half self-warms)
        int i = half_ * 100000 + nb * 256 + tid;
        if (i < NN * 2) { float4 v = ((const float4*)gsl)[i]; pf = v.x; }
    }
    asm volatile("" : "+v"(pf));

    int nloc = nb * 128 + wave * 32 + nsub;
    if (nloc >= NN / 2) return;
    int n = half_ * (NN / 2) + nloc;
    int s0 = start[n], s1 = start[n + 1];
    float inv = 1.0f / (float)max(s1 - s0, 1);
    float a[8] = {0.f, 0.f, 0.f, 0.f, 0.f, 0.f, 0.f, 0.f};
    int i = s0;
    for (; i + 4 <= s1; i += 4) {
        int c0 = idx[i], c1 = idx[i + 1], c2 = idx[i + 2], c3 = idx[i + 3];
        half8 v0 = gsl[(size_t)c0 * 2 + f4];
        half8 v1 = gsl[(size_t)c1 * 2 + f4];
        half8 v2 = gsl[(size_t)c2 * 2 + f4];
        half8 v3 = gsl[(size_t)c3 * 2 + f4];
#pragma unroll
        for (int k = 0; k < 8; ++k)
            a[k] += ((float)v0[k] + (float)v1[k]) + ((float)v2[k] + (float)v3[k]);
    }
    for (; i < s1; ++i) {
        half8 v = gsl[(size_t)idx[i] * 2 + f4];
#pragma unroll
        for (int k = 0; k < 8; ++k) a[k] += (float)v[k];
    }
    float4 o0, o1;
    o0.x = a[0] * inv; o0.y = a[1] * inv; o0.z = a[2] * inv; o0.w = a[3] * inv;
    o1.x = a[4] * inv; o1.y = a[5] * inv; o1.z = a[6] * inv; o1.w = a[7] * inv;
    float4* op = (float4*)(aggT + ((size_t)(2 * c + f4) * NN + n) * 8);
    op[0] = o0; op[1] = o1;
}

// ---------------- layer-1 linear (+ReLU) -> fp16 h1 ----------------
// round-2-proven register shape: 8 chunks x (8 agg + 8 root floats), prefetch pair.
// agg fp32 [8][NN][8]; root = emb[x[n]] fp32 row. Output h1 fp16 [4][NN][16],
// chunk h = dims h*16..h*16+15 (exactly this y-slice's dims).
__global__ void __launch_bounds__(256) k_lin1(const float* __restrict__ aggT,
        const int* __restrict__ x, const float4* __restrict__ emb4,
        const float* __restrict__ Wl, const float* __restrict__ bl,
        const float* __restrict__ Wr, half8* __restrict__ outh) {
    int tid = blockIdx.x * 256 + threadIdx.x;
    int h = blockIdx.y;                // 0..3
    int n = tid < NN ? tid : NN - 1;   // clamp; store guarded

    float acc[16];
#pragma unroll
    for (int d = 0; d < 16; ++d) acc[d] = bl[h * 16 + d];

    const float4* ap = (const float4*)aggT + (size_t)n * 2;
    const float4* rp = emb4 + (size_t)x[n] * 16;
    const size_t cstep = (size_t)NN * 2;   // agg slab stride in float4s
    const float* WlH = Wl + h * 16 * 64;
    const float* WrH = Wr + h * 16 * 64;

    float4 a0 = ap[0], a1 = ap[1], r0 = rp[0], r1 = rp[1];
    for (int c = 0; c < 8; ++c) {
        float av[8] = {a0.x, a0.y, a0.z, a0.w, a1.x, a1.y, a1.z, a1.w};
        float rv[8] = {r0.x, r0.y, r0.z, r0.w, r1.x, r1.y, r1.z, r1.w};
        if (c < 7) {
            size_t offA = (size_t)(c + 1) * cstep;
            a0 = ap[offA]; a1 = ap[offA + 1];
            r0 = rp[(c + 1) * 2]; r1 = rp[(c + 1) * 2 + 1];
        }
        const float* wlc = WlH + c * 8;   // local row d, cols c*8..c*8+7
        const float* wrc = WrH + c * 8;
#pragma unroll
        for (int d = 0; d < 16; ++d) {
#pragma unroll
            for (int k = 0; k < 8; ++k) {
                acc[d] += av[k] * wlc[d * 64 + k];
                acc[d] += rv[k] * wrc[d * 64 + k];
            }
        }
    }

    if (tid < NN) {
        half8 o0, o1;
#pragma unroll
        for (int k = 0; k < 8; ++k) {
            o0[k] = (_Float16)fmaxf(acc[k], 0.f);
            o1[k] = (_Float16)fmaxf(acc[8 + k], 0.f);
        }
        half8* op = outh + ((size_t)h * NN + n) * 2;
        op[0] = o0; op[1] = o1;
    }
}

// ---------------- layer-2 linear FUSED with per-graph pool ----------------
// round-2 register shape. agg fp32 [8][NN][8]; root = h1 fp16 [4][NN][16]
// (chunk c -> h1 chunk c>>1, half c&1: one half8 = dims 8c..8c+7).
// After ReLU: wave-level segmented scan over sorted batch; segment-last lane
// atomAdds into pooled. Writes nothing else -> no in-place hazard.
__global__ void __launch_bounds__(256) k_lin2p(const float* __restrict__ aggT,
        const half8* __restrict__ rooth, const int* __restrict__ batch,
        const float* __restrict__ Wl, const float* __restrict__ bl,
        const float* __restrict__ Wr, float* __restrict__ pooled) {
    int tid = blockIdx.x * 256 + threadIdx.x;
    int h = blockIdx.y;                // 0..3
    bool valid = tid < NN;
    int n = valid ? tid : NN - 1;      // clamp; contribution zeroed below

    float acc[16];
#pragma unroll
    for (int d = 0; d < 16; ++d) acc[d] = bl[h * 16 + d];

    const float4* ap = (const float4*)aggT + (size_t)n * 2;
    const half8*  rp = rooth + (size_t)n * 2;
    const size_t cstep  = (size_t)NN * 2;   // agg slab stride in float4s
    const size_t rcstep = (size_t)NN * 2;   // h1 chunk stride in half8s
    const float* WlH = Wl + h * 16 * 64;
    const float* WrH = Wr + h * 16 * 64;

    float4 a0 = ap[0], a1 = ap[1];
    half8 rh = rp[0];
    for (int c = 0; c < 8; ++c) {
        float av[8] = {a0.x, a0.y, a0.z, a0.w, a1.x, a1.y, a1.z, a1.w};
        float rv[8];
#pragma unroll
        for (int k = 0; k < 8; ++k) rv[k] = (float)rh[k];
        if (c < 7) {
            size_t offA = (size_t)(c + 1) * cstep;
            a0 = ap[offA]; a1 = ap[offA + 1];
            int cn = c + 1;
            rh = rp[(size_t)(cn >> 1) * rcstep + (cn & 1)];
        }
        const float* wlc = WlH + c * 8;
        const float* wrc = WrH + c * 8;
#pragma unroll
        for (int d = 0; d < 16; ++d) {
#pragma unroll
            for (int k = 0; k < 8; ++k) {
                acc[d] += av[k] * wlc[d * 64 + k];
                acc[d] += rv[k] * wrc[d * 64 + k];
            }
        }
    }

    // ---- fused pool: segmented wave scan over sorted batch ----
    int lane = threadIdx.x & 63;
    int g = batch[n];
    int g1  = __shfl_up(g, 1);
    int g2  = __shfl_up(g, 2);
    int g4  = __shfl_up(g, 4);
    int g8  = __shfl_up(g, 8);
    int g16 = __shfl_up(g, 16);
    int g32 = __shfl_up(g, 32);
    bool s1  = (lane >= 1)  && (g1 == g);
    bool s2  = (lane >= 2)  && (g2 == g);
    bool s4  = (lane >= 4)  && (g4 == g);
    bool s8  = (lane >= 8)  && (g8 == g);
    bool s16 = (lane >= 16) && (g16 == g);
    bool s32 = (lane >= 32) && (g32 == g);
    int gn = __shfl_down(g, 1);
    bool isLast = (lane == 63) || (gn != g);
    float* pg = pooled + (size_t)g * D + h * 16;
#pragma unroll
    for (int d = 0; d < 16; ++d) {
        float v = valid ? fmaxf(acc[d], 0.f) : 0.f;
        float t;
        t = __shfl_up(v, 1);  v += s1  ? t : 0.f;
        t = __shfl_up(v, 2);  v += s2  ? t : 0.f;
        t = __shfl_up(v, 4);  v += s4  ? t : 0.f;
        t = __shfl_up(v, 8);  v += s8  ? t : 0.f;
        t = __shfl_up(v, 16); v += s16 ? t : 0.f;
        t = __shfl_up(v, 32); v += s32 ? t : 0.f;
        if (isLast) atomAddF(pg + d, v);
    }
}

// ---------------- readout ----------------
__global__ void __launch_bounds__(256) k_bounds(const int* __restrict__ batch, int* __restrict__ gs) {
    int n = blockIdx.x * blockDim.x + threadIdx.x;
    if (n >= NN) return;
    int b = batch[n];
    if (n == 0) {
        for (int g = 0; g <= b; ++g) gs[g] = 0;
    } else {
        int bp = batch[n - 1];
        for (int g = bp + 1; g <= b; ++g) gs[g] = n;
    }
    if (n == NN - 1) {
        for (int g = b + 1; g <= NG; ++g) gs[g] = NN;
    }
}

__global__ void __launch_bounds__(256) k_out(const int* __restrict__ gs,
        const float* __restrict__ pooled, const float* __restrict__ Wout,
        const float* __restrict__ bout, float* __restrict__ out) {
    int lane = threadIdx.x & 63;
    int wave = threadIdx.x >> 6;
    int g = blockIdx.x * 4 + wave;       // 512 blocks
    int s0 = gs[g], s1 = gs[g + 1];
    float p = pooled[(size_t)g * D + lane] / (float)max(s1 - s0, 1);
    float c0 = p * Wout[lane];
    float c1 = p * Wout[D + lane];
#pragma unroll
    for (int off = 32; off > 0; off >>= 1) {
        c0 += __shfl_down(c0, off, 64);
        c1 += __shfl_down(c1, off, 64);
    }
    if (lane == 0) {
        out[g * C + 0] = c0 + bout[0];
        out[g * C + 1] = c1 + bout[1];
    }
}

extern "C" void kernel_launch(void* const* d_in, const int* in_sizes, int n_in,
                              void* d_out, int out_size, void* d_ws, size_t ws_size,
                              hipStream_t stream) {
    const int*   x     = (const int*)d_in[0];
    const int*   src   = (const int*)d_in[1];
    const int*   dst   = src + NE;
    const int*   batch = (const int*)d_in[2];
    const float* emb   = (const float*)d_in[3];
    const float* W1l   = (const float*)d_in[4];
    const float* b1l   = (const float*)d_in[5];
    const float* W1r   = (const float*)d_in[6];
    const float* W2l   = (const float*)d_in[7];
    const float* b2l   = (const float*)d_in[8];
    const float* W2r   = (const float*)d_in[9];
    const float* Wout  = (const float*)d_in[10];
    const float* bout  = (const float*)d_in[11];
    float* out = (float*)d_out;

    float*    TA   = (float*)d_ws;                          // NN*64 fp32 agg slabs [8][NN][8]
    _Float16* T0h  = (_Float16*)(TA + (size_t)NN * 64);     // NN*64 fp16 h1 [4][NN][16]
    _Float16* embh = T0h + (size_t)NN * 64;                 // VOCAB*64 fp16
    float* pooled  = (float*)(embh + (size_t)VOCAB * 64);   // NG*64
    int* bcur   = (int*)(pooled + (size_t)NG * 64);         // NBK (contiguous w/ pooled for memset)
    int* bstart = bcur + NBK;                               // NBK+1
    int* startA = bstart + NBK + 1;                         // NN+1
    int* gs     = startA + NN + 1;                          // NG+1
    int* csr    = gs + NG + 1;                              // NE
    unsigned short* xcsr = (unsigned short*)(csr + NE);     // NE u16
    unsigned* barr = (unsigned*)(xcsr + NE);                // NBK*SLOT (~5.6 MB)

    hipMemsetAsync(pooled, 0, ((size_t)NG * 64 + NBK) * sizeof(float), stream);

    k_embh  <<<(VOCAB * 8 + 255) / 256, 256, 0, stream>>>((const float4*)emb, (half8*)embh);
    k_bucket<<<192, 256, 0, stream>>>(src, dst, bcur, barr);
    k_bscan <<<1, 256, 0, stream>>>(bcur, bstart, startA);
    k_sortb <<<NBK, 256, 0, stream>>>(bcur, bstart, barr, x, startA, csr, xcsr);
    k_bounds<<<(NN + 255) / 256, 256, 0, stream>>>(batch, gs);

    dim3 linGrid((NN + 255) / 256, 4);
    // ---- layer 1: full-row fp16 gather from emb_h; root from fp32 emb[x[n]] ----
    k_agg1<<<NN / 32, 256, 0, stream>>>(startA, xcsr, (const half8*)embh, TA);
    k_lin1<<<linGrid, 256, 0, stream>>>(TA, x, (const float4*)emb,
                                        W1l, b1l, W1r, (half8*)T0h);
    // ---- layer 2: 4-chunk fp16 gather; linear fused with per-graph pool ----
    k_agg2h<<<((NN / 2 + 127) / 128) * 8, 256, 0, stream>>>(startA, csr, (const half8*)T0h, TA);
    k_lin2p<<<linGrid, 256, 0, stream>>>(TA, (const half8*)T0h, batch,
                                         W2l, b2l, W2r, pooled);

    // ---- readout ----
    k_out<<<NG / 4, 256, 0, stream>>>(gs, pooled, Wout, bout, out);
}

// Round 5
// 255.221 us; speedup vs baseline: 1.4641x; 1.0385x over previous
//
#include <hip/hip_runtime.h>

#define NN 100000
#define NE 1200000
#define NG 2048
#define VOCAB 10000
#define D 64
#define C 2

#define NBK 196      // coarse buckets of 512 nodes (dst >> 9)
#define BSH 9
#define SLOT 7168    // per-bucket slot stride; mean 6144, sd 78 -> +13 sigma

typedef _Float16 half8 __attribute__((ext_vector_type(8)));

__device__ __forceinline__ int atomAddI(int* p, int v) {
    return __hip_atomic_fetch_add(p, v, __ATOMIC_RELAXED, __HIP_MEMORY_SCOPE_AGENT);
}
__device__ __forceinline__ void atomAddF(float* p, float v) {
    __hip_atomic_fetch_add(p, v, __ATOMIC_RELAXED, __HIP_MEMORY_SCOPE_AGENT);
}

// ---------------- emb -> fp16 copy (1.28 MB, L2-resident everywhere) ----------------
__global__ void __launch_bounds__(256) k_embh(const float4* __restrict__ emb4,
        half8* __restrict__ embh) {
    int i = blockIdx.x * 256 + threadIdx.x;
    if (i >= VOCAB * 8) return;
    float4 a = emb4[(size_t)i * 2], b = emb4[(size_t)i * 2 + 1];
    half8 h;
    h[0] = (_Float16)a.x; h[1] = (_Float16)a.y; h[2] = (_Float16)a.z; h[3] = (_Float16)a.w;
    h[4] = (_Float16)b.x; h[5] = (_Float16)b.y; h[6] = (_Float16)b.z; h[7] = (_Float16)b.w;
    embh[i] = h;
}

// ---------------- phase A: coarse bucket scatter (packed src|dlow) ----------------
__global__ void __launch_bounds__(256) k_bucket(const int* __restrict__ src,
        const int* __restrict__ dst, int* __restrict__ bcur, unsigned* __restrict__ barr) {
    __shared__ int hcnt[NBK], hbase[NBK], hrank[NBK];
    int tid = threadIdx.x;
    if (tid < NBK) { hcnt[tid] = 0; hrank[tid] = 0; }
    __syncthreads();
    int per = (NE + gridDim.x - 1) / gridDim.x;
    int e0 = blockIdx.x * per, e1 = min(e0 + per, NE);
    for (int e = e0 + tid; e < e1; e += 256)
        atomicAdd(&hcnt[dst[e] >> BSH], 1);
    __syncthreads();
    if (tid < NBK) {
        int c = hcnt[tid];
        hbase[tid] = c ? atomAddI(&bcur[tid], c) : 0;
    }
    __syncthreads();
    for (int e = e0 + tid; e < e1; e += 256) {
        int d = dst[e], s = src[e];
        int b = d >> BSH;
        int r = atomicAdd(&hrank[b], 1);
        barr[(size_t)b * SLOT + hbase[b] + r] = ((unsigned)s << BSH) | (unsigned)(d & 511);
    }
}

// ---------------- bucket-count scan ----------------
__global__ void __launch_bounds__(256) k_bscan(const int* __restrict__ bcur,
        int* __restrict__ bstart, int* __restrict__ start) {
    __shared__ int sm[256];
    int t = threadIdx.x;
    int v0 = (t < NBK) ? bcur[t] : 0;
    sm[t] = v0;
    __syncthreads();
    for (int off = 1; off < 256; off <<= 1) {
        int v = (t >= off) ? sm[t - off] : 0;
        __syncthreads();
        sm[t] += v;
        __syncthreads();
    }
    if (t < NBK) bstart[t] = sm[t] - v0;
    if (t == 0) { bstart[NBK] = NE; start[NN] = NE; }
}

// ---------------- phase B: exact CSR within each bucket; also emits u16 xcsr ----------------
__global__ void __launch_bounds__(256) k_sortb(const int* __restrict__ bcur,
        const int* __restrict__ bstart, const unsigned* __restrict__ barr,
        const int* __restrict__ x,
        int* __restrict__ start, int* __restrict__ csr, unsigned short* __restrict__ xcsr) {
    __shared__ int cnt[512], loc[512], sm[256];
    int t = threadIdx.x;
    int b = blockIdx.x;
    cnt[t] = 0; cnt[t + 256] = 0;
    __syncthreads();
    int count = bcur[b];
    int base  = bstart[b];
    const unsigned* bp = barr + (size_t)b * SLOT;
    for (int i = t; i < count; i += 256)
        atomicAdd(&cnt[bp[i] & 511], 1);
    __syncthreads();
    int c0 = cnt[2 * t], c1 = cnt[2 * t + 1];
    int s = c0 + c1;
    sm[t] = s;
    __syncthreads();
    for (int off = 1; off < 256; off <<= 1) {
        int v = (t >= off) ? sm[t - off] : 0;
        __syncthreads();
        sm[t] += v;
        __syncthreads();
    }
    int ex = sm[t] - s;
    loc[2 * t] = ex; loc[2 * t + 1] = ex + c0;
    int g0 = b << BSH;
    if (g0 + 2 * t < NN)     start[g0 + 2 * t]     = base + ex;
    if (g0 + 2 * t + 1 < NN) start[g0 + 2 * t + 1] = base + ex + c0;
    __syncthreads();
    for (int i = t; i < count; i += 256) {
        unsigned p = bp[i];
        int r = atomicAdd(&loc[p & 511], 1);
        int sn = (int)(p >> BSH);
        csr[base + r]  = sn;
        xcsr[base + r] = (unsigned short)x[sn];   // VOCAB=10000 < 65536
    }
}

// ---------------- layer-1 aggregate: FULL 128B fp16 row gather from emb_h ----------------
// emb_h = 1.28 MB -> L2-resident on every XCD. 8 lanes x half8 per row,
// 8 nodes/wave, 32 nodes/block. 2 line-touches per edge.
// Output agg layout: fp16 [8][NN][8] (slab s = dims 8s..8s+7).
__global__ void __launch_bounds__(256) k_agg1(const int* __restrict__ start,
        const unsigned short* __restrict__ idx, const half8* __restrict__ embh,
        half8* __restrict__ aggh) {
    int tid = threadIdx.x;
    int lane = tid & 63, wave = tid >> 6;
    int f = lane & 7;          // which half8 of the 64-dim row
    int nsub = lane >> 3;      // 8 nodes per wave
    int n = blockIdx.x * 32 + wave * 8 + nsub;

    float pf = 0.f;
    {   // streaming warm of emb_h (covered once device-wide; rest self-warms)
        int i = blockIdx.x * 256 + tid;
        if (i < VOCAB * 8) { float4 v = ((const float4*)embh)[i]; pf = v.x; }
    }
    asm volatile("" : "+v"(pf));
    if (n >= NN) return;

    int s0 = start[n], s1 = start[n + 1];
    float inv = 1.0f / (float)max(s1 - s0, 1);
    float a[8] = {0.f, 0.f, 0.f, 0.f, 0.f, 0.f, 0.f, 0.f};
    int i = s0;
    for (; i + 4 <= s1; i += 4) {
        int c0 = idx[i], c1 = idx[i + 1], c2 = idx[i + 2], c3 = idx[i + 3];
        half8 v0 = embh[(size_t)c0 * 8 + f];
        half8 v1 = embh[(size_t)c1 * 8 + f];
        half8 v2 = embh[(size_t)c2 * 8 + f];
        half8 v3 = embh[(size_t)c3 * 8 + f];
#pragma unroll
        for (int k = 0; k < 8; ++k)
            a[k] += ((float)v0[k] + (float)v1[k]) + ((float)v2[k] + (float)v3[k]);
    }
    for (; i < s1; ++i) {
        half8 v = embh[(size_t)idx[i] * 8 + f];
#pragma unroll
        for (int k = 0; k < 8; ++k) a[k] += (float)v[k];
    }
    half8 o;
#pragma unroll
    for (int k = 0; k < 8; ++k) o[k] = (_Float16)(a[k] * inv);
    aggh[(size_t)f * NN + n] = o;
}

// ---------------- layer-2 aggregate: 4-chunk fp16 gather from h1 ----------------
// h1 chunk slab = NN*16 fp16 = 3.2 MB (per-XCD L2-resident). c = bid&3,
// node-half = bid bit2 -> each XCD streams only half the csr (idx fetch halved).
// 2 lanes x half8 per chunk-row; 32 nodes/wave. 4 line-touches/edge.
// Output agg fp16 [8][NN][8]: slab 2c+f4 = dims 16c+8*f4 .. +7.
__global__ void __launch_bounds__(256) k_agg2h(const int* __restrict__ start,
        const int* __restrict__ idx, const half8* __restrict__ gsrc,
        half8* __restrict__ aggh) {
    int tid = threadIdx.x;
    int lane = tid & 63, wave = tid >> 6;
    int c     = blockIdx.x & 3;
    int half_ = (blockIdx.x >> 2) & 1;
    int nb    = blockIdx.x >> 3;         // 0..390
    int f4 = lane & 1, nsub = lane >> 1; // 32 nodes per wave
    const half8* gsl = gsrc + (size_t)c * NN * 2;

    float pf = 0.f;
    {   // warm this XCD's share of the chunk slab (other half self-warms)
        int i = half_ * 100000 + nb * 256 + tid;
        if (i < NN * 2) { float4 v = ((const float4*)gsl)[i]; pf = v.x; }
    }
    asm volatile("" : "+v"(pf));

    int nloc = nb * 128 + wave * 32 + nsub;
    if (nloc >= NN / 2) return;
    int n = half_ * (NN / 2) + nloc;
    int s0 = start[n], s1 = start[n + 1];
    float inv = 1.0f / (float)max(s1 - s0, 1);
    float a[8] = {0.f, 0.f, 0.f, 0.f, 0.f, 0.f, 0.f, 0.f};
    int i = s0;
    for (; i + 4 <= s1; i += 4) {
        int c0 = idx[i], c1 = idx[i + 1], c2 = idx[i + 2], c3 = idx[i + 3];
        half8 v0 = gsl[(size_t)c0 * 2 + f4];
        half8 v1 = gsl[(size_t)c1 * 2 + f4];
        half8 v2 = gsl[(size_t)c2 * 2 + f4];
        half8 v3 = gsl[(size_t)c3 * 2 + f4];
#pragma unroll
        for (int k = 0; k < 8; ++k)
            a[k] += ((float)v0[k] + (float)v1[k]) + ((float)v2[k] + (float)v3[k]);
    }
    for (; i < s1; ++i) {
        half8 v = gsl[(size_t)idx[i] * 2 + f4];
#pragma unroll
        for (int k = 0; k < 8; ++k) a[k] += (float)v[k];
    }
    half8 o;
#pragma unroll
    for (int k = 0; k < 8; ++k) o[k] = (_Float16)(a[k] * inv);
    aggh[(size_t)(2 * c + f4) * NN + n] = o;
}

// ---------------- layer-1 linear (+ReLU) -> fp16 h1 ----------------
// proven register shape: 8 slabs x (8 agg + 8 root), prefetch pair.
// agg fp16 [8][NN][8] (cvt once per load, reused 16x in d-loop);
// root = emb[x[n]] fp32 row. Output h1 fp16 [4][NN][16], chunk h = this slice's dims.
__global__ void __launch_bounds__(256) k_lin1(const half8* __restrict__ aggh,
        const int* __restrict__ x, const float4* __restrict__ emb4,
        const float* __restrict__ Wl, const float* __restrict__ bl,
        const float* __restrict__ Wr, half8* __restrict__ outh) {
    int tid = blockIdx.x * 256 + threadIdx.x;
    int h = blockIdx.y;                // 0..3
    int n = tid < NN ? tid : NN - 1;   // clamp; store guarded

    float acc[16];
#pragma unroll
    for (int d = 0; d < 16; ++d) acc[d] = bl[h * 16 + d];

    const half8*  ap = aggh + n;           // slab stride NN (half8 units)
    const float4* rp = emb4 + (size_t)x[n] * 16;
    const float* WlH = Wl + h * 16 * 64;
    const float* WrH = Wr + h * 16 * 64;

    half8 ah = ap[0];
    float4 r0 = rp[0], r1 = rp[1];
    for (int c = 0; c < 8; ++c) {
        float av[8], rv[8];
#pragma unroll
        for (int k = 0; k < 8; ++k) av[k] = (float)ah[k];
        rv[0] = r0.x; rv[1] = r0.y; rv[2] = r0.z; rv[3] = r0.w;
        rv[4] = r1.x; rv[5] = r1.y; rv[6] = r1.z; rv[7] = r1.w;
        if (c < 7) {
            ah = ap[(size_t)(c + 1) * NN];
            r0 = rp[(c + 1) * 2]; r1 = rp[(c + 1) * 2 + 1];
        }
        const float* wlc = WlH + c * 8;   // local row d, cols c*8..c*8+7
        const float* wrc = WrH + c * 8;
#pragma unroll
        for (int d = 0; d < 16; ++d) {
#pragma unroll
            for (int k = 0; k < 8; ++k) {
                acc[d] += av[k] * wlc[d * 64 + k];
                acc[d] += rv[k] * wrc[d * 64 + k];
            }
        }
    }

    if (tid < NN) {
        half8 o0, o1;
#pragma unroll
        for (int k = 0; k < 8; ++k) {
            o0[k] = (_Float16)fmaxf(acc[k], 0.f);
            o1[k] = (_Float16)fmaxf(acc[8 + k], 0.f);
        }
        half8* op = outh + ((size_t)h * NN + n) * 2;
        op[0] = o0; op[1] = o1;
    }
}

// ---------------- layer-2 linear FUSED with per-graph pool ----------------
// agg fp16 [8][NN][8]; root = h1 fp16 [4][NN][16] (slab c -> h1 chunk c>>1, half c&1).
// After ReLU: wave-level segmented scan over sorted batch; segment-last lane
// atomAdds into pooled. Writes nothing else -> no in-place hazard.
__global__ void __launch_bounds__(256) k_lin2p(const half8* __restrict__ aggh,
        const half8* __restrict__ rooth, const int* __restrict__ batch,
        const float* __restrict__ Wl, const float* __restrict__ bl,
        const float* __restrict__ Wr, float* __restrict__ pooled) {
    int tid = blockIdx.x * 256 + threadIdx.x;
    int h = blockIdx.y;                // 0..3
    bool valid = tid < NN;
    int n = valid ? tid : NN - 1;      // clamp; contribution zeroed below

    float acc[16];
#pragma unroll
    for (int d = 0; d < 16; ++d) acc[d] = bl[h * 16 + d];

    const half8* ap = aggh + n;             // slab stride NN
    const half8* rp = rooth + (size_t)n * 2;
    const size_t rcstep = (size_t)NN * 2;   // h1 chunk stride in half8s
    const float* WlH = Wl + h * 16 * 64;
    const float* WrH = Wr + h * 16 * 64;

    half8 ah = ap[0];
    half8 rh = rp[0];
    for (int c = 0; c < 8; ++c) {
        float av[8], rv[8];
#pragma unroll
        for (int k = 0; k < 8; ++k) { av[k] = (float)ah[k]; rv[k] = (float)rh[k]; }
        if (c < 7) {
            ah = ap[(size_t)(c + 1) * NN];
            int cn = c + 1;
            rh = rp[(size_t)(cn >> 1) * rcstep + (cn & 1)];
        }
        const float* wlc = WlH + c * 8;
        const float* wrc = WrH + c * 8;
#pragma unroll
        for (int d = 0; d < 16; ++d) {
#pragma unroll
            for (int k = 0; k < 8; ++k) {
                acc[d] += av[k] * wlc[d * 64 + k];
                acc[d] += rv[k] * wrc[d * 64 + k];
            }
        }
    }

    // ---- fused pool: segmented wave scan over sorted batch ----
    int lane = threadIdx.x & 63;
    int g = batch[n];
    int g1  = __shfl_up(g, 1);
    int g2  = __shfl_up(g, 2);
    int g4  = __shfl_up(g, 4);
    int g8  = __shfl_up(g, 8);
    int g16 = __shfl_up(g, 16);
    int g32 = __shfl_up(g, 32);
    bool s1  = (lane >= 1)  && (g1 == g);
    bool s2  = (lane >= 2)  && (g2 == g);
    bool s4  = (lane >= 4)  && (g4 == g);
    bool s8  = (lane >= 8)  && (g8 == g);
    bool s16 = (lane >= 16) && (g16 == g);
    bool s32 = (lane >= 32) && (g32 == g);
    int gn = __shfl_down(g, 1);
    bool isLast = (lane == 63) || (gn != g);
    float* pg = pooled + (size_t)g * D + h * 16;
#pragma unroll
    for (int d = 0; d < 16; ++d) {
        float v = valid ? fmaxf(acc[d], 0.f) : 0.f;
        float t;
        t = __shfl_up(v, 1);  v += s1  ? t : 0.f;
        t = __shfl_up(v, 2);  v += s2  ? t : 0.f;
        t = __shfl_up(v, 4);  v += s4  ? t : 0.f;
        t = __shfl_up(v, 8);  v += s8  ? t : 0.f;
        t = __shfl_up(v, 16); v += s16 ? t : 0.f;
        t = __shfl_up(v, 32); v += s32 ? t : 0.f;
        if (isLast) atomAddF(pg + d, v);
    }
}

// ---------------- readout ----------------
__global__ void __launch_bounds__(256) k_bounds(const int* __restrict__ batch, int* __restrict__ gs) {
    int n = blockIdx.x * blockDim.x + threadIdx.x;
    if (n >= NN) return;
    int b = batch[n];
    if (n == 0) {
        for (int g = 0; g <= b; ++g) gs[g] = 0;
    } else {
        int bp = batch[n - 1];
        for (int g = bp + 1; g <= b; ++g) gs[g] = n;
    }
    if (n == NN - 1) {
        for (int g = b + 1; g <= NG; ++g) gs[g] = NN;
    }
}

__global__ void __launch_bounds__(256) k_out(const int* __restrict__ gs,
        const float* __restrict__ pooled, const float* __restrict__ Wout,
        const float* __restrict__ bout, float* __restrict__ out) {
    int lane = threadIdx.x & 63;
    int wave = threadIdx.x >> 6;
    int g = blockIdx.x * 4 + wave;       // 512 blocks
    int s0 = gs[g], s1 = gs[g + 1];
    float p = pooled[(size_t)g * D + lane] / (float)max(s1 - s0, 1);
    float c0 = p * Wout[lane];
    float c1 = p * Wout[D + lane];
#pragma unroll
    for (int off = 32; off > 0; off >>= 1) {
        c0 += __shfl_down(c0, off, 64);
        c1 += __shfl_down(c1, off, 64);
    }
    if (lane == 0) {
        out[g * C + 0] = c0 + bout[0];
        out[g * C + 1] = c1 + bout[1];
    }
}

extern "C" void kernel_launch(void* const* d_in, const int* in_sizes, int n_in,
                              void* d_out, int out_size, void* d_ws, size_t ws_size,
                              hipStream_t stream) {
    const int*   x     = (const int*)d_in[0];
    const int*   src   = (const int*)d_in[1];
    const int*   dst   = src + NE;
    const int*   batch = (const int*)d_in[2];
    const float* emb   = (const float*)d_in[3];
    const float* W1l   = (const float*)d_in[4];
    const float* b1l   = (const float*)d_in[5];
    const float* W1r   = (const float*)d_in[6];
    const float* W2l   = (const float*)d_in[7];
    const float* b2l   = (const float*)d_in[8];
    const float* W2r   = (const float*)d_in[9];
    const float* Wout  = (const float*)d_in[10];
    const float* bout  = (const float*)d_in[11];
    float* out = (float*)d_out;

    _Float16* TAh  = (_Float16*)d_ws;                       // NN*64 fp16 agg slabs [8][NN][8]
    _Float16* T0h  = TAh + (size_t)NN * 64;                 // NN*64 fp16 h1 [4][NN][16]
    _Float16* embh = T0h + (size_t)NN * 64;                 // VOCAB*64 fp16
    float* pooled  = (float*)(embh + (size_t)VOCAB * 64);   // NG*64
    int* bcur   = (int*)(pooled + (size_t)NG * 64);         // NBK (contiguous w/ pooled for memset)
    int* bstart = bcur + NBK;                               // NBK+1
    int* startA = bstart + NBK + 1;                         // NN+1
    int* gs     = startA + NN + 1;                          // NG+1
    int* csr    = gs + NG + 1;                              // NE
    unsigned short* xcsr = (unsigned short*)(csr + NE);     // NE u16
    unsigned* barr = (unsigned*)(xcsr + NE);                // NBK*SLOT (~5.6 MB)

    hipMemsetAsync(pooled, 0, ((size_t)NG * 64 + NBK) * sizeof(float), stream);

    k_embh  <<<(VOCAB * 8 + 255) / 256, 256, 0, stream>>>((const float4*)emb, (half8*)embh);
    k_bucket<<<192, 256, 0, stream>>>(src, dst, bcur, barr);
    k_bscan <<<1, 256, 0, stream>>>(bcur, bstart, startA);
    k_sortb <<<NBK, 256, 0, stream>>>(bcur, bstart, barr, x, startA, csr, xcsr);
    k_bounds<<<(NN + 255) / 256, 256, 0, stream>>>(batch, gs);

    dim3 linGrid((NN + 255) / 256, 4);
    // ---- layer 1: full-row fp16 gather from emb_h; root from fp32 emb[x[n]] ----
    k_agg1<<<NN / 32, 256, 0, stream>>>(startA, xcsr, (const half8*)embh, (half8*)TAh);
    k_lin1<<<linGrid, 256, 0, stream>>>((const half8*)TAh, x, (const float4*)emb,
                                        W1l, b1l, W1r, (half8*)T0h);
    // ---- layer 2: 4-chunk fp16 gather; linear fused with per-graph pool ----
    k_agg2h<<<((NN / 2 + 127) / 128) * 8, 256, 0, stream>>>(startA, csr, (const half8*)T0h, (half8*)TAh);
    k_lin2p<<<linGrid, 256, 0, stream>>>((const half8*)TAh, (const half8*)T0h, batch,
                                         W2l, b2l, W2r, pooled);

    // ---- readout ----
    k_out<<<NG / 4, 256, 0, stream>>>(gs, pooled, Wout, bout, out);
}